// Round 1
// baseline (677.465 us; speedup 1.0000x reference)
//
#include <hip/hip_runtime.h>

typedef unsigned short u16;
typedef unsigned int u32;
typedef __attribute__((ext_vector_type(8))) __bf16 bf16x8;
typedef __attribute__((ext_vector_type(4))) float f32x4;

#define SEQ   2048
#define NH    71
#define HD    64
#define HID   4544   // 71*64
#define NQKV  4672   // 73*64

__device__ __forceinline__ u16 f2bf(float f) {
    __bf16 b = (__bf16)f;
    return __builtin_bit_cast(u16, b);
}

__device__ __forceinline__ void gload_lds16(const u16* g, u16* l) {
    __builtin_amdgcn_global_load_lds(
        (const __attribute__((address_space(1))) u32*)g,
        (__attribute__((address_space(3))) u32*)l, 16, 0, 0);
}

// ---------------- f32 -> bf16 elementwise (x) ----------------
__global__ __launch_bounds__(256) void k_convert(const float* __restrict__ in,
                                                 u16* __restrict__ out, int n4) {
    for (int i = blockIdx.x * 256 + threadIdx.x; i < n4; i += gridDim.x * 256) {
        float4 v = ((const float4*)in)[i];
        ushort4 o;
        o.x = f2bf(v.x); o.y = f2bf(v.y); o.z = f2bf(v.z); o.w = f2bf(v.w);
        ((ushort4*)out)[i] = o;
    }
}

// ------------- transpose+convert: in[R][C] f32 -> out[C][R] bf16 -------------
// R,C multiples of 32 for our shapes.
__global__ __launch_bounds__(256) void k_transpose(const float* __restrict__ in,
                                                   u16* __restrict__ out, int R, int C) {
    __shared__ float tile[32][33];
    int c0 = blockIdx.x * 32, r0 = blockIdx.y * 32;
    int tx = threadIdx.x & 31, ty = threadIdx.x >> 5;
#pragma unroll
    for (int i = 0; i < 32; i += 8)
        tile[ty + i][tx] = in[(size_t)(r0 + ty + i) * C + c0 + tx];
    __syncthreads();
#pragma unroll
    for (int i = 0; i < 32; i += 8)
        out[(size_t)(c0 + ty + i) * R + r0 + tx] = f2bf(tile[tx][ty + i]);
}

// ---- C[M][N] f32 = A[M][K] bf16 @ BT[N][K]^T (m97 structure, 128x128, BK=32) ----
// M%128==0, K%32==0. N guarded on store; BT rows padded so staging reads stay in ws.
__global__ __launch_bounds__(256) void k_gemm_bt(const u16* __restrict__ A,
                                                 const u16* __restrict__ BT,
                                                 float* __restrict__ C,
                                                 int M, int N, int K) {
    __shared__ u16 lsA[128 * 32];
    __shared__ u16 lsB[128 * 32];
    const int tid = threadIdx.x;
    const int lane = tid & 63;
    const int wid = tid >> 6;
    const int wr = wid >> 1, wc = wid & 1;   // 2x2 wave grid, 64x64 each
    const int l15 = lane & 15, lg = lane >> 4;
    const int m0 = blockIdx.y * 128;
    const int n0 = blockIdx.x * 128;

    f32x4 acc[4][4];
#pragma unroll
    for (int i = 0; i < 4; ++i)
#pragma unroll
        for (int j = 0; j < 4; ++j) acc[i][j] = (f32x4){0.f, 0.f, 0.f, 0.f};

    for (int k0 = 0; k0 < K; k0 += 32) {
#pragma unroll
        for (int i = 0; i < 2; ++i) {
            int ch = i * 256 + tid;       // 0..511 ; 4 16B-chunks per 32-elem row
            int row = ch >> 2;
            int c8 = ch & 3;
            gload_lds16(A + (size_t)(m0 + row) * K + k0 + c8 * 8, lsA + ch * 8);
            gload_lds16(BT + (size_t)(n0 + row) * K + k0 + c8 * 8, lsB + ch * 8);
        }
        __syncthreads();
        bf16x8 af[4], bfr[4];
#pragma unroll
        for (int mi = 0; mi < 4; ++mi)
            af[mi] = *(const bf16x8*)(lsA + (wr * 64 + mi * 16 + l15) * 32 + lg * 8);
#pragma unroll
        for (int ni = 0; ni < 4; ++ni)
            bfr[ni] = *(const bf16x8*)(lsB + (wc * 64 + ni * 16 + l15) * 32 + lg * 8);
#pragma unroll
        for (int mi = 0; mi < 4; ++mi)
#pragma unroll
            for (int ni = 0; ni < 4; ++ni)
                acc[mi][ni] = __builtin_amdgcn_mfma_f32_16x16x32_bf16(
                    af[mi], bfr[ni], acc[mi][ni], 0, 0, 0);
        __syncthreads();
    }
    // C layout: col = lane&15, row = (lane>>4)*4 + j  (m89-verified)
#pragma unroll
    for (int mi = 0; mi < 4; ++mi)
#pragma unroll
        for (int ni = 0; ni < 4; ++ni) {
            int row = m0 + wr * 64 + mi * 16 + lg * 4;
            int col = n0 + wc * 64 + ni * 16 + l15;
            if (col < N) {
#pragma unroll
                for (int j = 0; j < 4; ++j)
                    C[(size_t)(row + j) * N + col] = acc[mi][ni][j];
            }
        }
}

// ---------------- RoPE + split/transposed emit ----------------
// qkv f32 [2048][73][64] -> q bf16 [71][2048][64] (pre-scaled by 0.125),
// k bf16 [2048][64], vT bf16 [64][2048]
__global__ __launch_bounds__(256) void k_rope(const float* __restrict__ qkv,
                                              const float* __restrict__ cosb,
                                              const float* __restrict__ sinb,
                                              u16* __restrict__ qb, u16* __restrict__ kb,
                                              u16* __restrict__ vT) {
    int s = blockIdx.x;
    __shared__ float cs[64], sn[64];
    if (threadIdx.x < 64) {
        cs[threadIdx.x] = cosb[s * 64 + threadIdx.x];
        sn[threadIdx.x] = sinb[s * 64 + threadIdx.x];
    }
    __syncthreads();
    const float* row = qkv + (size_t)s * NQKV;
    for (int e = threadIdx.x; e < NQKV; e += 256) {
        int h = e >> 6, d = e & 63;
        float x = row[e];
        if (h < 72) {
            float other = row[h * 64 + ((d < 32) ? d + 32 : d - 32)];
            float rot = (d < 32) ? -other : other;
            float r = x * cs[d] + rot * sn[d];
            if (h < NH) qb[((size_t)h * SEQ + s) * 64 + d] = f2bf(r * 0.125f);
            else        kb[(size_t)s * 64 + d] = f2bf(r);
        } else {
            vT[(size_t)d * SEQ + s] = f2bf(x);
        }
    }
}

// ---------------- Flash attention (MQA: shared K/V) ----------------
// block = (qblk, head); 4 waves x 32 q-rows; KV tiles of 128; online softmax.
// LDS XOR-swizzled: 16B chunk c of row r stored at chunk c^(r&mask) -> 2-way max.
__global__ __launch_bounds__(256) void k_attn(const u16* __restrict__ qb,
                                              const u16* __restrict__ kb,
                                              const u16* __restrict__ vT,
                                              u16* __restrict__ ctx) {
    const int qblk = blockIdx.x;   // 0..15
    const int h = blockIdx.y;      // 0..70
    const int tid = threadIdx.x;
    const int lane = tid & 63;
    const int wid = tid >> 6;
    const int l15 = lane & 15, lg = lane >> 4;
    __shared__ u16 lsK[128 * 64];      // [t][d], swizzled rows of 128B
    __shared__ u16 lsV[64 * 128];      // [d][t], swizzled rows of 256B
    __shared__ u16 lsP[4 * 32 * 128];  // per-wave P [r][t], swizzled rows of 256B
    u16* myP = lsP + wid * (32 * 128);

    const int s0 = qblk * 128;
    const int srow0 = s0 + wid * 32;

    // Q fragments straight from global (A-frag: row=l&15, k=(l>>4)*8+j), q pre-scaled
    bf16x8 qf[2][2];
#pragma unroll
    for (int mi = 0; mi < 2; ++mi)
#pragma unroll
        for (int ks = 0; ks < 2; ++ks)
            qf[mi][ks] = *(const bf16x8*)(qb + ((size_t)h * SEQ + srow0 + mi * 16 + l15) * 64
                                          + ks * 32 + lg * 8);

    f32x4 oacc[2][4];
#pragma unroll
    for (int i = 0; i < 2; ++i)
#pragma unroll
        for (int j = 0; j < 4; ++j) oacc[i][j] = (f32x4){0.f, 0.f, 0.f, 0.f};
    float mrun[2][4], lrun[2][4];
#pragma unroll
    for (int i = 0; i < 2; ++i)
#pragma unroll
        for (int j = 0; j < 4; ++j) { mrun[i][j] = -1e30f; lrun[i][j] = 0.f; }

    for (int t = 0; t <= qblk; ++t) {
        const int t0 = t * 128;
        // stage K (128x64) and V^T (64x128), swizzled
#pragma unroll
        for (int i = 0; i < 4; ++i) {
            int ch = i * 256 + tid;     // 0..1023
            {
                int r = ch >> 3, c = ch & 7;
                uint4 v = *(const uint4*)(kb + (size_t)(t0 + r) * 64 + c * 8);
                *(uint4*)((char*)lsK + r * 128 + ((c * 16) ^ ((r & 7) << 4))) = v;
            }
            {
                int r = ch >> 4, c = ch & 15;
                uint4 v = *(const uint4*)(vT + (size_t)r * SEQ + t0 + c * 8);
                *(uint4*)((char*)lsV + r * 256 + ((c * 16) ^ ((r & 15) << 4))) = v;
            }
        }
        __syncthreads();

        // S = Q @ K^T : 32 x 128 per wave
        f32x4 sacc[2][8];
#pragma unroll
        for (int i = 0; i < 2; ++i)
#pragma unroll
            for (int j = 0; j < 8; ++j) sacc[i][j] = (f32x4){0.f, 0.f, 0.f, 0.f};
#pragma unroll
        for (int ks = 0; ks < 2; ++ks) {
            bf16x8 kf[8];
#pragma unroll
            for (int ni = 0; ni < 8; ++ni) {
                int r = ni * 16 + l15;
                kf[ni] = *(const bf16x8*)((const char*)lsK + r * 128
                                          + ((ks * 64 + lg * 16) ^ ((r & 7) << 4)));
            }
#pragma unroll
            for (int mi = 0; mi < 2; ++mi)
#pragma unroll
                for (int ni = 0; ni < 8; ++ni)
                    sacc[mi][ni] = __builtin_amdgcn_mfma_f32_16x16x32_bf16(
                        qf[mi][ks], kf[ni], sacc[mi][ni], 0, 0, 0);
        }

        if (t == qblk) {  // causal mask on diagonal tile only
#pragma unroll
            for (int mi = 0; mi < 2; ++mi)
#pragma unroll
                for (int ni = 0; ni < 8; ++ni)
#pragma unroll
                    for (int j = 0; j < 4; ++j) {
                        int srow = srow0 + mi * 16 + lg * 4 + j;
                        int tcol = t0 + ni * 16 + l15;
                        if (tcol > srow) sacc[mi][ni][j] = -1e9f;
                    }
        }

        // online softmax; each lane owns rows (lg*4+j) of its two 16-row blocks
#pragma unroll
        for (int mi = 0; mi < 2; ++mi)
#pragma unroll
            for (int j = 0; j < 4; ++j) {
                float m = sacc[mi][0][j];
#pragma unroll
                for (int ni = 1; ni < 8; ++ni) m = fmaxf(m, sacc[mi][ni][j]);
#pragma unroll
                for (int off = 1; off < 16; off <<= 1) m = fmaxf(m, __shfl_xor(m, off, 64));
                float mnew = fmaxf(m, mrun[mi][j]);
                float alpha = __expf(mrun[mi][j] - mnew);
                mrun[mi][j] = mnew;
                float rs = 0.f;
#pragma unroll
                for (int ni = 0; ni < 8; ++ni) {
                    float p = __expf(sacc[mi][ni][j] - mnew);
                    sacc[mi][ni][j] = p;
                    rs += p;
                }
#pragma unroll
                for (int off = 1; off < 16; off <<= 1) rs += __shfl_xor(rs, off, 64);
                lrun[mi][j] = lrun[mi][j] * alpha + rs;
#pragma unroll
                for (int ni = 0; ni < 4; ++ni) oacc[mi][ni][j] *= alpha;
            }

        // P -> wave-private LDS (bf16, swizzled); same-wave DS ops are in-order
#pragma unroll
        for (int mi = 0; mi < 2; ++mi)
#pragma unroll
            for (int ni = 0; ni < 8; ++ni)
#pragma unroll
                for (int j = 0; j < 4; ++j) {
                    int r = mi * 16 + lg * 4 + j;
                    int cb = (ni * 16 + l15) * 2;
                    *(u16*)((char*)myP + r * 256 + (cb ^ ((r & 7) << 4))) =
                        f2bf(sacc[mi][ni][j]);
                }

        // O += P @ V
#pragma unroll
        for (int ks = 0; ks < 4; ++ks) {
            bf16x8 pf[2], vf[4];
#pragma unroll
            for (int mi = 0; mi < 2; ++mi) {
                int r = mi * 16 + l15;
                pf[mi] = *(const bf16x8*)((const char*)myP + r * 256
                                          + ((ks * 64 + lg * 16) ^ ((r & 7) << 4)));
            }
#pragma unroll
            for (int nd = 0; nd < 4; ++nd) {
                int r = nd * 16 + l15;
                vf[nd] = *(const bf16x8*)((const char*)lsV + r * 256
                                          + ((ks * 64 + lg * 16) ^ ((r & 15) << 4)));
            }
#pragma unroll
            for (int mi = 0; mi < 2; ++mi)
#pragma unroll
                for (int nd = 0; nd < 4; ++nd)
                    oacc[mi][nd] = __builtin_amdgcn_mfma_f32_16x16x32_bf16(
                        pf[mi], vf[nd], oacc[mi][nd], 0, 0, 0);
        }
        __syncthreads();
    }

    // epilogue: ctx[s][h*64+d] = O / l
#pragma unroll
    for (int mi = 0; mi < 2; ++mi)
#pragma unroll
        for (int nd = 0; nd < 4; ++nd)
#pragma unroll
            for (int j = 0; j < 4; ++j) {
                int srow = srow0 + mi * 16 + lg * 4 + j;
                int col = h * 64 + nd * 16 + l15;
                ctx[(size_t)srow * HID + col] = f2bf(oacc[mi][nd][j] / lrun[mi][j]);
            }
}

extern "C" void kernel_launch(void* const* d_in, const int* in_sizes, int n_in,
                              void* d_out, int out_size, void* d_ws, size_t ws_size,
                              hipStream_t stream) {
    const float* hs      = (const float*)d_in[0];   // [1,1,2048,4544]
    // d_in[1] attention_mask unused (causal reconstructed on device)
    const float* w_qkv   = (const float*)d_in[2];   // [4544][4672]
    const float* w_dense = (const float*)d_in[3];   // [4544][4544]
    const float* cosb    = (const float*)d_in[4];   // [2048][64]
    const float* sinb    = (const float*)d_in[5];   // [2048][64]
    float* out = (float*)d_out;                     // [2048][4544] f32

    char* ws = (char*)d_ws;
    // workspace layout (bytes); total 160,940,032
    u16*   x_bf  = (u16*)(ws + 0);            // [2048][4544] bf16; reused as ctx later
    u16*   wqkvT = (u16*)(ws + 18612224);     // [4736][4544] bf16 (4672 real rows + pad)
    u16*   wdenT = (u16*)(ws + 61652992);     // [4608][4544] bf16 (4544 real rows + pad)
    float* qkv   = (float*)(ws + 103530496);  // [2048][4672] f32
    u16*   q_bf  = (u16*)(ws + 141803520);    // [71][2048][64] bf16
    u16*   k_bf  = (u16*)(ws + 160415744);    // [2048][64] bf16
    u16*   vT_bf = (u16*)(ws + 160677888);    // [64][2048] bf16

    k_convert<<<2048, 256, 0, stream>>>(hs, x_bf, (SEQ * HID) / 4);
    k_transpose<<<dim3(NQKV / 32, HID / 32), 256, 0, stream>>>(w_qkv, wqkvT, HID, NQKV);
    k_transpose<<<dim3(HID / 32, HID / 32), 256, 0, stream>>>(w_dense, wdenT, HID, HID);
    k_gemm_bt<<<dim3(37, 16), 256, 0, stream>>>(x_bf, wqkvT, qkv, SEQ, NQKV, HID);
    k_rope<<<SEQ, 256, 0, stream>>>(qkv, cosb, sinb, q_bf, k_bf, vT_bf);
    k_attn<<<dim3(16, NH), 256, 0, stream>>>(q_bf, k_bf, vT_bf, x_bf /*ctx*/);
    k_gemm_bt<<<dim3(36, 16), 256, 0, stream>>>(x_bf /*ctx*/, wdenT, out, SEQ, HID, HID);
}